// Round 1
// 1098.331 us; speedup vs baseline: 1.4988x; 1.4988x over previous
//
#include <hip/hip_runtime.h>

#define B_ 2
#define I_ 2048
#define M_ 2048
#define D_ 1024
#define H_ 16
#define Dh_ 64
#define SSTR 2052  // 2048 + 4 pad: 4*l16 stride -> 2-way LDS banks (free)

typedef __bf16 bf16_t;
typedef __bf16 bf16x8 __attribute__((ext_vector_type(8)));
typedef __bf16 bf16x4 __attribute__((ext_vector_type(4)));
typedef float f32x4 __attribute__((ext_vector_type(4)));

// float -> bf16 round-to-nearest-even (manual, avoids relying on fptrunc semantics)
__device__ __forceinline__ bf16_t f2b(float f) {
    union { float f; unsigned u; } in;
    in.f = f;
    unsigned r = (in.u + 0x7fffu + ((in.u >> 16) & 1u)) >> 16;
    union { unsigned short s; bf16_t b; } out;
    out.s = (unsigned short)r;
    return out.b;
}

// ---------------- cast fp32 -> bf16 (vectorized) ----------------
__global__ void cast_f32_bf16(const float* __restrict__ src, bf16_t* __restrict__ dst, int n) {
    int idx = (blockIdx.x * blockDim.x + threadIdx.x) * 4;
    if (idx + 3 < n) {
        float4 v = *(const float4*)(src + idx);
        bf16x4 o;
        o[0] = f2b(v.x); o[1] = f2b(v.y); o[2] = f2b(v.z); o[3] = f2b(v.w);
        *(bf16x4*)(dst + idx) = o;
    }
}

// ---------------- transpose 1024x1024 fp32 -> bf16 (Wt[n][k] = W[k][n]) ----------------
__global__ void transpose_cast(const float* __restrict__ src, bf16_t* __restrict__ dst) {
    __shared__ float tile[32][33];
    int n0 = blockIdx.x * 32, k0 = blockIdx.y * 32;
    int tx = threadIdx.x, ty = threadIdx.y;  // 32 x 8
#pragma unroll
    for (int i = 0; i < 4; i++)
        tile[ty + i * 8][tx] = src[(size_t)(k0 + ty + i * 8) * D_ + n0 + tx];
    __syncthreads();
#pragma unroll
    for (int i = 0; i < 4; i++)
        dst[(size_t)(n0 + ty + i * 8) * D_ + k0 + tx] = f2b(tile[tx][ty + i * 8]);
}

// ---------------- NT GEMM: C[m][n] = sum_k A[m][k] * Bt[n][k]  (128x128 tile) ----------
// MODE 0: bf16 row-major out [RM x 1024], scaled
// MODE 1: bf16 out written as Vt[((b*16+h)*64+d)*2048 + m]
// MODE 2: fp32 row-major out
template <int MODE>
__global__ __launch_bounds__(256) void gemm_nt(const bf16_t* __restrict__ A,
                                               const bf16_t* __restrict__ Bt,
                                               void* __restrict__ Cout, float scale) {
    constexpr int LDT = 40;  // 32 + 8 pad (keeps 16B alignment, spreads banks)
    __shared__ bf16_t As[128 * LDT];
    __shared__ bf16_t Bs[128 * LDT];
    int m0 = blockIdx.x * 128, n0 = blockIdx.y * 128;
    int tid = threadIdx.x;
    int wave = tid >> 6, lane = tid & 63, quad = lane >> 4, l16 = lane & 15;
    int wr = wave >> 1, wc = wave & 1;
    f32x4 acc[4][4] = {};

    for (int k0 = 0; k0 < D_; k0 += 32) {
        // stage A and Bt tiles: 128 rows x 32 k each, 16B chunks
#pragma unroll
        for (int c = tid; c < 512; c += 256) {
            int r = c >> 2, ko = (c & 3) * 8;
            *(bf16x8*)&As[r * LDT + ko] = *(const bf16x8*)&A[(size_t)(m0 + r) * D_ + k0 + ko];
            *(bf16x8*)&Bs[r * LDT + ko] = *(const bf16x8*)&Bt[(size_t)(n0 + r) * D_ + k0 + ko];
        }
        __syncthreads();
        bf16x8 af[4], bfr[4];
#pragma unroll
        for (int i = 0; i < 4; i++) af[i] = *(bf16x8*)&As[(wr * 64 + i * 16 + l16) * LDT + quad * 8];
#pragma unroll
        for (int j = 0; j < 4; j++) bfr[j] = *(bf16x8*)&Bs[(wc * 64 + j * 16 + l16) * LDT + quad * 8];
#pragma unroll
        for (int i = 0; i < 4; i++)
#pragma unroll
            for (int j = 0; j < 4; j++)
                acc[i][j] = __builtin_amdgcn_mfma_f32_16x16x32_bf16(af[i], bfr[j], acc[i][j], 0, 0, 0);
        __syncthreads();
    }

#pragma unroll
    for (int i = 0; i < 4; i++)
#pragma unroll
        for (int j = 0; j < 4; j++) {
            int n = n0 + wc * 64 + j * 16 + l16;
#pragma unroll
            for (int r = 0; r < 4; r++) {
                int m = m0 + wr * 64 + i * 16 + quad * 4 + r;
                float v = acc[i][j][r] * scale;
                if (MODE == 0) {
                    ((bf16_t*)Cout)[(size_t)m * D_ + n] = f2b(v);
                } else if (MODE == 1) {
                    int b = m >> 11, mm = m & 2047, h = n >> 6, d = n & 63;
                    ((bf16_t*)Cout)[(((size_t)(b * H_ + h) * Dh_ + d) << 11) + mm] = f2b(v);
                } else {
                    ((float*)Cout)[(size_t)m * D_ + n] = v;
                }
            }
        }
}

// ---------------- fused attention: S=QK^T+bias, softmax, write align, PV --------------
// 1024 threads (16 waves) per block: LDS (128 KiB S tile) limits us to 1 block/CU,
// so pack 4 waves/SIMD into that one block (occupancy 12.5% -> 50%) for latency hiding.
__global__ __launch_bounds__(1024) void attn_fused(const bf16_t* __restrict__ Q,
                                                   const bf16_t* __restrict__ K,
                                                   const bf16_t* __restrict__ Vt,
                                                   const float* __restrict__ bias,
                                                   float* __restrict__ align_out,
                                                   bf16_t* __restrict__ AO) {
    extern __shared__ float S[];  // 16 * SSTR floats
    __shared__ float rowinv[16];
    int i0 = blockIdx.x * 16, h = blockIdx.y, b = blockIdx.z;
    int tid = threadIdx.x, wave = tid >> 6, lane = tid & 63, quad = lane >> 4, l16 = lane & 15;

    // Q A-fragments (16 rows x Dh=64), shared by all waves
    size_t qrow = (size_t)(b * I_ + i0 + l16) * D_ + h * Dh_ + quad * 8;
    bf16x8 aq0 = *(const bf16x8*)&Q[qrow];
    bf16x8 aq1 = *(const bf16x8*)&Q[qrow + 32];

    // ---- QK^T: each wave does 8 consecutive m-tiles (m in [wave*128, wave*128+128)) ----
#pragma unroll
    for (int t = 0; t < 8; t++) {
        int m0 = wave * 128 + t * 16;
        size_t krow = (size_t)(b * M_ + m0 + l16) * D_ + h * Dh_ + quad * 8;
        bf16x8 bk0 = *(const bf16x8*)&K[krow];
        bf16x8 bk1 = *(const bf16x8*)&K[krow + 32];
        f32x4 acc = {};
        acc = __builtin_amdgcn_mfma_f32_16x16x32_bf16(aq0, bk0, acc, 0, 0, 0);
        acc = __builtin_amdgcn_mfma_f32_16x16x32_bf16(aq1, bk1, acc, 0, 0, 0);
#pragma unroll
        for (int r = 0; r < 4; r++) {
            int i = quad * 4 + r;
            float v = acc[r] + bias[((size_t)b * I_ + i0 + i) * M_ + m0 + l16];
            S[i * SSTR + m0 + l16] = v;
        }
    }
    __syncthreads();

    // ---- softmax stats: one full wave per row, 64-lane shuffle reduce ----
    {
        int row = wave;
        float* srow = &S[row * SSTR];
        float mx = -1e30f;
#pragma unroll
        for (int t = 0; t < 8; t++) {
            float4 v = *(float4*)&srow[lane * 4 + t * 256];
            mx = fmaxf(mx, fmaxf(fmaxf(v.x, v.y), fmaxf(v.z, v.w)));
        }
#pragma unroll
        for (int off = 1; off < 64; off <<= 1) mx = fmaxf(mx, __shfl_xor(mx, off));
        float sum = 0.f;
#pragma unroll
        for (int t = 0; t < 8; t++) {
            float4 v = *(float4*)&srow[lane * 4 + t * 256];
            v.x = __expf(v.x - mx); v.y = __expf(v.y - mx);
            v.z = __expf(v.z - mx); v.w = __expf(v.w - mx);
            *(float4*)&srow[lane * 4 + t * 256] = v;
            sum += v.x + v.y + v.z + v.w;
        }
#pragma unroll
        for (int off = 1; off < 64; off <<= 1) sum += __shfl_xor(sum, off);
        if (lane == 0) rowinv[row] = 1.0f / sum;
    }
    __syncthreads();

    // ---- write align block (16 x 2048 fp32, contiguous float4 stores) ----
    {
        float* dst = align_out + (((size_t)(b * H_ + h) * I_ + i0) << 11);
        for (int idx = tid; idx < 16 * 2048 / 4; idx += 1024) {
            int r = idx >> 9;
            int c = (idx & 511) * 4;
            float4 v = *(float4*)&S[r * SSTR + c];
            float iv = rowinv[r];
            v.x *= iv; v.y *= iv; v.z *= iv; v.w *= iv;
            *(float4*)&dst[((size_t)r << 11) + c] = v;
        }
    }

    // ---- PV: wave = (ktgroup, colgroup); partial accumulate then LDS reduce ----
    {
        int cg = wave & 3, kg = wave >> 2;
        int n0 = cg * 16;
        f32x4 o0 = {}, o1 = {};
        const bf16_t* vrow = &Vt[((size_t)(b * H_ + h) * Dh_ + n0 + l16) << 11];
#pragma unroll
        for (int t = 0; t < 8; t++) {
            int kt = kg * 512 + t * 64;
            const float* arow = &S[l16 * SSTR + kt + quad * 8];
            bf16x8 a0, a1;
#pragma unroll
            for (int j = 0; j < 8; j++) a0[j] = f2b(arow[j]);
#pragma unroll
            for (int j = 0; j < 8; j++) a1[j] = f2b(arow[32 + j]);
            bf16x8 v0 = *(const bf16x8*)&vrow[kt + quad * 8];
            bf16x8 v1 = *(const bf16x8*)&vrow[kt + 32 + quad * 8];
            o0 = __builtin_amdgcn_mfma_f32_16x16x32_bf16(a0, v0, o0, 0, 0, 0);
            o1 = __builtin_amdgcn_mfma_f32_16x16x32_bf16(a1, v1, o1, 0, 0, 0);
        }
        __syncthreads();  // all reads of S complete; safe to reuse S as scratch
        float* scr = &S[(size_t)wave * 512 + (size_t)lane * 8];
        *(f32x4*)scr = o0;
        *(f32x4*)(scr + 4) = o1;
        __syncthreads();
        if (kg == 0) {
#pragma unroll
            for (int w2 = 1; w2 < 4; w2++) {
                const float* p = &S[(size_t)(w2 * 4 + cg) * 512 + (size_t)lane * 8];
                f32x4 p0 = *(const f32x4*)p;
                f32x4 p1 = *(const f32x4*)(p + 4);
                o0 += p0;
                o1 += p1;
            }
#pragma unroll
            for (int r = 0; r < 4; r++) {
                int i = quad * 4 + r;
                float v = (o0[r] + o1[r]) * rowinv[i];
                AO[(size_t)(b * I_ + i0 + i) * D_ + h * Dh_ + n0 + l16] = f2b(v);
            }
        }
    }
}

extern "C" void kernel_launch(void* const* d_in, const int* in_sizes, int n_in,
                              void* d_out, int out_size, void* d_ws, size_t ws_size,
                              hipStream_t stream) {
    const float* input  = (const float*)d_in[0];
    const float* memory = (const float*)d_in[1];
    const float* bias   = (const float*)d_in[2];
    const float* Wq     = (const float*)d_in[3];
    const float* Wk     = (const float*)d_in[4];
    const float* Wv     = (const float*)d_in[5];
    const float* Wo     = (const float*)d_in[6];

    float* out   = (float*)d_out;
    float* align = out + (size_t)B_ * I_ * D_;

    char* ws = (char*)d_ws;
    const size_t nBID = (size_t)B_ * I_ * D_;   // 4,194,304
    const size_t nDD  = (size_t)D_ * D_;        // 1,048,576
    bf16_t* in_b  = (bf16_t*)ws; ws += nBID * 2;
    bf16_t* mem_b = (bf16_t*)ws; ws += nBID * 2;
    bf16_t* Wq_t  = (bf16_t*)ws; ws += nDD * 2;
    bf16_t* Wk_t  = (bf16_t*)ws; ws += nDD * 2;
    bf16_t* Wv_t  = (bf16_t*)ws; ws += nDD * 2;
    bf16_t* Wo_t  = (bf16_t*)ws; ws += nDD * 2;
    bf16_t* Qb    = (bf16_t*)ws; ws += nBID * 2;
    bf16_t* Kb    = (bf16_t*)ws; ws += nBID * 2;
    bf16_t* Vt    = (bf16_t*)ws; ws += nBID * 2;
    bf16_t* AO    = (bf16_t*)ws; ws += nBID * 2;

    // casts
    cast_f32_bf16<<<nBID / 1024, 256, 0, stream>>>(input, in_b, (int)nBID);
    cast_f32_bf16<<<nBID / 1024, 256, 0, stream>>>(memory, mem_b, (int)nBID);
    dim3 tb(32, 8), tg(32, 32);
    transpose_cast<<<tg, tb, 0, stream>>>(Wq, Wq_t);
    transpose_cast<<<tg, tb, 0, stream>>>(Wk, Wk_t);
    transpose_cast<<<tg, tb, 0, stream>>>(Wv, Wv_t);
    transpose_cast<<<tg, tb, 0, stream>>>(Wo, Wo_t);

    // projections: [4096,1024] @ [1024,1024]^T-layout
    dim3 gg(32, 8);
    gemm_nt<0><<<gg, 256, 0, stream>>>(in_b, Wq_t, Qb, 0.125f);   // Dh^-0.5 folded
    gemm_nt<0><<<gg, 256, 0, stream>>>(mem_b, Wk_t, Kb, 1.0f);
    gemm_nt<1><<<gg, 256, 0, stream>>>(mem_b, Wv_t, Vt, 1.0f);    // per-head transposed

    // fused attention: 1024 threads/block (16 waves), 128 KiB dynamic LDS
    attn_fused<<<dim3(I_ / 16, H_, B_), 1024, 16 * SSTR * 4, stream>>>(Qb, Kb, Vt, bias, align, AO);

    // output projection (fp32 out)
    gemm_nt<2><<<gg, 256, 0, stream>>>(AO, Wo_t, out, 1.0f);
}